// Round 6
// baseline (219.128 us; speedup 1.0000x reference)
//
#include <hip/hip_runtime.h>

typedef short short8 __attribute__((ext_vector_type(8)));
typedef float f32x4 __attribute__((ext_vector_type(4)));

#define NROWS 32768
#define DIM 32
#define KCODES 8192
#define FLAG_CAP 16384
#define EPS_REL (1.0f/4096.0f)   // flag margin 2^-12; packed-score error bound ~2^-14·norm
#define NBLK 1024                // main grid: 1024 blocks x 32 rows

// ws layout (bytes)
#define WS_EHI  0
#define WS_ELO  (512*1024)
#define WS_PART (1024*1024)            // 1024 floats
#define WS_CNT  (WS_PART + 4096)       // cnt[0]=flag count, cnt[1]=refine ticket
#define WS_LIST (WS_CNT + 64)          // FLAG_CAP ints
#define WS_CORR (WS_LIST + FLAG_CAP*4) // FLAG_CAP floats

__device__ __forceinline__ unsigned short bf16_rne(float v){
    unsigned int u = __float_as_uint(v);
    unsigned int r = (u + 0x7fffu + ((u >> 16) & 1u)) >> 16;
    return (unsigned short)r;
}
__device__ __forceinline__ float bf16_to_f(unsigned short h){
    return __uint_as_float(((unsigned int)h) << 16);
}
__device__ __forceinline__ float dot4(const float4& a, const float4& b){
    return fmaf(a.w, b.w, fmaf(a.z, b.z, fmaf(a.y, b.y, a.x * b.x)));
}

// ------------- prep: codebook hi/lo bf16 split (thread = code x quarter) -----
__global__ __launch_bounds__(256) void vq_prep(
    const float* __restrict__ emb,
    unsigned short* __restrict__ ehi, unsigned short* __restrict__ elo,
    int* __restrict__ cnt)
{
    int tid = blockIdx.x * 256 + threadIdx.x;   // 0..32767
    if (tid < 2) cnt[tid] = 0;
    int r  = tid >> 2;
    int qt = tid & 3;
    const float* er = emb + (size_t)r * DIM + qt * 8;
    float4 v0 = *(const float4*)er;
    float4 v1 = *(const float4*)(er + 4);
    float f[8] = {v0.x, v0.y, v0.z, v0.w, v1.x, v1.y, v1.z, v1.w};
    short8 a, b;
    #pragma unroll
    for (int j = 0; j < 8; j++){
        unsigned short h = bf16_rne(f[j]);
        a[j] = (short)h;
        b[j] = (short)bf16_rne(f[j] - bf16_to_f(h));
    }
    *(short8*)(ehi + (size_t)r * DIM + qt * 8) = a;
    *(short8*)(elo + (size_t)r * DIM + qt * 8) = b;
}

// ---------------- main: MFMA argmax + fused gather/loss epilogue -------------
// 1024 blocks x 8 waves, 32 rows/block (2 rowgroups). Wave w scans codes
// [w*1024,(w+1)*1024) as 64 tiles of 16 codes. Bias 2*norm in MFMA C keeps
// scores positive so packed (score&~63 | 63-t) uints order correctly with
// first-occurrence tie-break.
#define PROC(bhv, blv, tcs)                                                      \
  {                                                                              \
    unsigned int tcv = (unsigned int)(tcs);                                      \
    _Pragma("unroll")                                                            \
    for (int rg = 0; rg < 2; ++rg){                                              \
      f32x4 acc = __builtin_amdgcn_mfma_f32_16x16x32_bf16(ahi[rg], bhv, cbias[rg], 0, 0, 0); \
      acc = __builtin_amdgcn_mfma_f32_16x16x32_bf16(ahi[rg], blv, acc, 0, 0, 0); \
      acc = __builtin_amdgcn_mfma_f32_16x16x32_bf16(alo[rg], bhv, acc, 0, 0, 0); \
      _Pragma("unroll")                                                          \
      for (int q = 0; q < 4; ++q){                                               \
        unsigned int u = (__float_as_uint(acc[q]) & maskv) | tcv;                \
        int rr = rg * 4 + q;                                                     \
        unsigned int nv2;                                                        \
        asm("v_med3_u32 %0, %1, %2, %3" : "=v"(nv2) : "v"(u), "v"(v1[rr]), "v"(v2[rr])); \
        v2[rr] = nv2;                                                            \
        v1[rr] = max(u, v1[rr]);                                                 \
      }                                                                          \
    }                                                                            \
  }

__global__ __launch_bounds__(512, 8) void vq_main_mfma(
    const float* __restrict__ inputs,
    const unsigned short* __restrict__ ehi,
    const unsigned short* __restrict__ elo,
    const float* __restrict__ emb,
    float* __restrict__ out_q, float* __restrict__ out_idx,
    float* __restrict__ part, int* __restrict__ cnt, int* __restrict__ list)
{
    const int L = threadIdx.x & 63;
    const int w = threadIdx.x >> 6;
    const int rowbase = blockIdx.x * 32;

    __shared__ float snorm[32];
    __shared__ unsigned int sv1[8][32];
    __shared__ unsigned int sv2[8][32];
    __shared__ int          scol[8][32];

    // A fragments + per-row norms (all waves load the same 32 rows)
    short8 ahi[2], alo[2];
    #pragma unroll
    for (int rg = 0; rg < 2; ++rg){
        const float* xr = inputs + (size_t)(rowbase + rg*16 + (L & 15)) * DIM + (L >> 4) * 8;
        float4 p0 = *(const float4*)xr;
        float4 p1 = *(const float4*)(xr + 4);
        float f[8] = {p0.x, p0.y, p0.z, p0.w, p1.x, p1.y, p1.z, p1.w};
        short8 h, l;
        #pragma unroll
        for (int i = 0; i < 8; i++){
            unsigned short hb = bf16_rne(f[i]);
            h[i] = (short)hb;
            l[i] = (short)bf16_rne(f[i] - bf16_to_f(hb));
        }
        ahi[rg] = h; alo[rg] = l;
        float s = dot4(p0, p0) + dot4(p1, p1);
        s += __shfl_xor(s, 16, 64);
        s += __shfl_xor(s, 32, 64);
        if (w == 0 && (L >> 4) == 0) snorm[rg*16 + L] = sqrtf(s);
    }
    __syncthreads();

    f32x4 cbias[2];
    #pragma unroll
    for (int rg = 0; rg < 2; ++rg){
        #pragma unroll
        for (int q = 0; q < 4; ++q)
            cbias[rg][q] = 2.0f * snorm[rg*16 + (L >> 4)*4 + q];
    }

    unsigned int maskv = 0xFFFFFFC0u;
    asm("" : "+v"(maskv));   // pin mask in VGPR so (x & m) | t fuses to v_and_or_b32

    unsigned int v1[8], v2[8];
    #pragma unroll
    for (int r = 0; r < 8; r++){ v1[r] = 0u; v2[r] = 0u; }

    const int c0 = w * 1024;
    const unsigned short* ehp = ehi + (size_t)(c0 + (L & 15)) * DIM + (L >> 4) * 8;
    const unsigned short* elp = elo + (size_t)(c0 + (L & 15)) * DIM + (L >> 4) * 8;

    for (int t = 0; t < 64; t += 2){
        short8 b0h = *(const short8*)(ehp);
        short8 b0l = *(const short8*)(elp);
        short8 b1h = *(const short8*)(ehp + 512);
        short8 b1l = *(const short8*)(elp + 512);
        ehp += 1024; elp += 1024;
        PROC(b0h, b0l, 63 - t);
        PROC(b1h, b1l, 62 - t);
    }

    // in-register reduction over the 16 cols (lane&15), exact top-2 merge
    unsigned int p1[8];
    #pragma unroll
    for (int r = 0; r < 8; r++) p1[r] = v1[r];
    #pragma unroll
    for (int m = 1; m < 16; m <<= 1){
        #pragma unroll
        for (int r = 0; r < 8; r++){
            unsigned int ov1 = __shfl_xor(v1[r], m, 64);
            unsigned int ov2 = __shfl_xor(v2[r], m, 64);
            unsigned int mn = min(v1[r], ov1);
            v2[r] = max(max(v2[r], ov2), mn);
            v1[r] = max(v1[r], ov1);
        }
    }
    // recover winning col via ballot (lowest matching lane = lowest col = first occurrence)
    int colr[8];
    #pragma unroll
    for (int r = 0; r < 8; r++){
        unsigned long long bm = __ballot(p1[r] == v1[r]);
        unsigned int grp = (unsigned int)((bm >> ((L >> 4) << 4)) & 0xFFFFull);
        colr[r] = __ffs(grp) - 1;
    }

    if ((L & 15) == 0){
        #pragma unroll
        for (int rg = 0; rg < 2; ++rg){
            #pragma unroll
            for (int q = 0; q < 4; ++q){
                int row = rg*16 + (L >> 4)*4 + q;   // C row = (lane>>4)*4 + reg
                sv1[w][row] = v1[rg*4 + q];
                sv2[w][row] = v2[rg*4 + q];
                scol[w][row] = colr[rg*4 + q];
            }
        }
    }
    __syncthreads();

    // epilogue (threads 0..31): merge 8 wave-slices, gather, loss, flag
    if (threadIdx.x < 32){
        int r = threadIdx.x;
        unsigned int b1 = 0u, b2 = 0u; int bw = 0, bc = 0;
        #pragma unroll
        for (int s = 0; s < 8; ++s){
            unsigned int u1 = sv1[s][r];
            unsigned int u2 = sv2[s][r];
            unsigned int mn = min(b1, u1);
            b2 = max(max(b2, u2), mn);
            bool g = u1 > b1;
            if (g){ b1 = u1; bw = s; bc = scol[s][r]; }
        }
        int t = 63 - (int)(b1 & 63u);
        int k = bw*1024 + t*16 + bc;
        int row = rowbase + r;
        out_idx[row] = (float)k;

        // gather code row, write quantized output, per-row squared error
        const float4* ep = (const float4*)(emb + (size_t)k * DIM);
        const float4* xr = (const float4*)(inputs + (size_t)row * DIM);
        float4* oq = (float4*)(out_q + (size_t)row * DIM);
        float s = 0.f;
        #pragma unroll
        for (int i = 0; i < 8; i++){
            float4 q = ep[i], x = xr[i];
            oq[i] = q;
            float dx = q.x - x.x, dy = q.y - x.y, dz = q.z - x.z, dw = q.w - x.w;
            s += dx*dx + dy*dy + dz*dz + dw*dw;
        }

        // flag near-ties for exact fp32 refinement
        float f1 = __uint_as_float(b1 & 0xFFFFFFC0u);
        float f2 = __uint_as_float(b2 & 0xFFFFFFC0u);
        if (f1 - f2 <= snorm[r] * EPS_REL){
            int pos = atomicAdd(cnt, 1);
            if (pos < FLAG_CAP) list[pos] = row;
        }

        // 32-lane reduction of the block's loss partial
        #pragma unroll
        for (int off = 16; off; off >>= 1) s += __shfl_down(s, off, 64);
        if (r == 0) part[blockIdx.x] = s;
    }
}

// -------- refine: exact fp32 argmax for flagged rows + patch + loss sum ------
__global__ __launch_bounds__(256) void vq_refine(
    const float* __restrict__ inputs, const float* __restrict__ emb,
    float* __restrict__ out_q, float* __restrict__ out_idx,
    const int* __restrict__ list, int* __restrict__ cnt,
    float* __restrict__ corrd, const float* __restrict__ part,
    float* __restrict__ out_loss)
{
    int n = cnt[0]; if (n > FLAG_CAP) n = FLAG_CAP;
    __shared__ float sv[4]; __shared__ int si[4];
    __shared__ int sbi;
    for (int j = blockIdx.x; j < n; j += gridDim.x){
        int row = list[j];
        const float4* xr = (const float4*)(inputs + (size_t)row * DIM);
        float4 x0 = xr[0], x1 = xr[1], x2 = xr[2], x3 = xr[3];
        float4 x4 = xr[4], x5 = xr[5], x6 = xr[6], x7 = xr[7];
        float bv = -3.0e38f; int bi = 0x7fffffff;
        for (int c = threadIdx.x; c < KCODES; c += 256){
            const float4* ep = (const float4*)(emb + (size_t)c * DIM);
            float d = dot4(x0, ep[0]) + dot4(x1, ep[1]) + dot4(x2, ep[2]) + dot4(x3, ep[3])
                    + dot4(x4, ep[4]) + dot4(x5, ep[5]) + dot4(x6, ep[6]) + dot4(x7, ep[7]);
            if (d > bv || (d == bv && c < bi)){ bv = d; bi = c; }
        }
        #pragma unroll
        for (int off = 32; off; off >>= 1){
            float ov = __shfl_down(bv, off, 64);
            int   oi = __shfl_down(bi, off, 64);
            if (ov > bv || (ov == bv && oi < bi)){ bv = ov; bi = oi; }
        }
        if ((threadIdx.x & 63) == 0){ sv[threadIdx.x >> 6] = bv; si[threadIdx.x >> 6] = bi; }
        __syncthreads();
        if (threadIdx.x == 0){
            #pragma unroll
            for (int q = 1; q < 4; q++){
                if (sv[q] > bv || (sv[q] == bv && si[q] < bi)){ bv = sv[q]; bi = si[q]; }
            }
            sbi = bi;
        }
        __syncthreads();
        int knew = sbi;
        int kold = (int)out_idx[row];
        // lanes 0..31: per-element loss delta; patch row if index changed
        if (threadIdx.x < 32){
            float x  = inputs[(size_t)row * DIM + threadIdx.x];
            float en = emb[(size_t)knew * DIM + threadIdx.x];
            float eo = emb[(size_t)kold * DIM + threadIdx.x];
            float d  = (en - x)*(en - x) - (eo - x)*(eo - x);
            #pragma unroll
            for (int off = 16; off; off >>= 1) d += __shfl_down(d, off, 64);
            if (knew != kold) out_q[(size_t)row * DIM + threadIdx.x] = en;
            if (threadIdx.x == 0){
                corrd[j] = (knew != kold) ? d : 0.0f;
                if (knew != kold) out_idx[row] = (float)knew;
            }
        }
        __syncthreads();
    }

    // last-block loss finalize (ticket)
    __shared__ int tkt;
    if (threadIdx.x == 0){
        __threadfence();
        tkt = atomicAdd(cnt + 1, 1);
    }
    __syncthreads();
    if (tkt == (int)gridDim.x - 1){
        __threadfence();
        float s = 0.f;
        for (int i = threadIdx.x; i < NBLK; i += 256) s += part[i];
        for (int j = threadIdx.x; j < n; j += 256) s += corrd[j];
        #pragma unroll
        for (int off = 32; off; off >>= 1) s += __shfl_down(s, off, 64);
        __shared__ float sp[4];
        if ((threadIdx.x & 63) == 0) sp[threadIdx.x >> 6] = s;
        __syncthreads();
        if (threadIdx.x == 0)
            *out_loss = (sp[0] + sp[1] + sp[2] + sp[3]) * (1.0f / ((float)NROWS * (float)DIM));
    }
}

extern "C" void kernel_launch(void* const* d_in, const int* in_sizes, int n_in,
                              void* d_out, int out_size, void* d_ws, size_t ws_size,
                              hipStream_t stream) {
    const float* inputs = (const float*)d_in[0];
    const float* emb    = (const float*)d_in[1];
    float* out      = (float*)d_out;
    float* out_q    = out;                       // [32768*32]
    float* out_loss = out + (size_t)NROWS * DIM; // [1]
    float* out_idx  = out_loss + 1;              // [32768] as float

    char* ws = (char*)d_ws;
    unsigned short* ehi   = (unsigned short*)(ws + WS_EHI);
    unsigned short* elo   = (unsigned short*)(ws + WS_ELO);
    float*          part  = (float*)(ws + WS_PART);
    int*            cnt   = (int*)(ws + WS_CNT);
    int*            list  = (int*)(ws + WS_LIST);
    float*          corrd = (float*)(ws + WS_CORR);

    vq_prep     <<<dim3(128),  dim3(256), 0, stream>>>(emb, ehi, elo, cnt);
    vq_main_mfma<<<dim3(NBLK), dim3(512), 0, stream>>>(inputs, ehi, elo, emb,
                                                       out_q, out_idx, part, cnt, list);
    vq_refine   <<<dim3(256),  dim3(256), 0, stream>>>(inputs, emb, out_q, out_idx,
                                                       list, cnt, corrd, part, out_loss);
}

// Round 7
// 129.873 us; speedup vs baseline: 1.6872x; 1.6872x over previous
//
#include <hip/hip_runtime.h>

typedef short short8 __attribute__((ext_vector_type(8)));
typedef float f32x4 __attribute__((ext_vector_type(4)));

#define NROWS 32768
#define DIM 32
#define KCODES 8192
#define FLAG_CAP 16384
#define EPS_REL (1.0f/4096.0f)   // flag margin 2^-12; packed-score error bound ~2^-14·norm
#define NBLK 1024                // main grid: 1024 blocks x 32 rows

// ws layout (bytes)
#define WS_EHI  0
#define WS_ELO  (512*1024)
#define WS_PART (1024*1024)            // 1024 floats
#define WS_CNT  (WS_PART + 4096)       // cnt[0]=flag count, cnt[1]=refine ticket
#define WS_LIST (WS_CNT + 64)          // FLAG_CAP ints
#define WS_CORR (WS_LIST + FLAG_CAP*4) // FLAG_CAP floats

__device__ __forceinline__ unsigned short bf16_rne(float v){
    unsigned int u = __float_as_uint(v);
    unsigned int r = (u + 0x7fffu + ((u >> 16) & 1u)) >> 16;
    return (unsigned short)r;
}
__device__ __forceinline__ float bf16_to_f(unsigned short h){
    return __uint_as_float(((unsigned int)h) << 16);
}
__device__ __forceinline__ float dot4(const float4& a, const float4& b){
    return fmaf(a.w, b.w, fmaf(a.z, b.z, fmaf(a.y, b.y, a.x * b.x)));
}

// ------------- prep: codebook hi/lo bf16 split (thread = code x quarter) -----
__global__ __launch_bounds__(256) void vq_prep(
    const float* __restrict__ emb,
    unsigned short* __restrict__ ehi, unsigned short* __restrict__ elo,
    int* __restrict__ cnt)
{
    int tid = blockIdx.x * 256 + threadIdx.x;   // 0..32767
    if (tid < 2) cnt[tid] = 0;
    int r  = tid >> 2;
    int qt = tid & 3;
    const float* er = emb + (size_t)r * DIM + qt * 8;
    float4 v0 = *(const float4*)er;
    float4 v1 = *(const float4*)(er + 4);
    float f[8] = {v0.x, v0.y, v0.z, v0.w, v1.x, v1.y, v1.z, v1.w};
    short8 a, b;
    #pragma unroll
    for (int j = 0; j < 8; j++){
        unsigned short h = bf16_rne(f[j]);
        a[j] = (short)h;
        b[j] = (short)bf16_rne(f[j] - bf16_to_f(h));
    }
    *(short8*)(ehi + (size_t)r * DIM + qt * 8) = a;
    *(short8*)(elo + (size_t)r * DIM + qt * 8) = b;
}

// ---------------- main: MFMA argmax + fused gather/loss epilogue -------------
// 1024 blocks x 8 waves, 32 rows/block (2 rowgroups). Wave w scans codes
// [w*1024,(w+1)*1024) as 64 tiles of 16 codes. Bias 2*norm in MFMA C keeps
// scores positive so packed (score&~63 | 63-t) uints order correctly with
// first-occurrence tie-break.
// NOTE: launch_bounds min-waves MUST stay at 4: forcing 8 caps VGPRs at 64 and
// the ~60-VGPR working set spills to scratch (round-6: 125 MB WRITE_SIZE, 3x
// slower). At (512,4) the natural VGPR count still lets HW run 6-8 waves/SIMD.
#define PROC(bhv, blv, tcs)                                                      \
  {                                                                              \
    unsigned int tcv = (unsigned int)(tcs);                                      \
    _Pragma("unroll")                                                            \
    for (int rg = 0; rg < 2; ++rg){                                              \
      f32x4 acc = __builtin_amdgcn_mfma_f32_16x16x32_bf16(ahi[rg], bhv, cbias[rg], 0, 0, 0); \
      acc = __builtin_amdgcn_mfma_f32_16x16x32_bf16(ahi[rg], blv, acc, 0, 0, 0); \
      acc = __builtin_amdgcn_mfma_f32_16x16x32_bf16(alo[rg], bhv, acc, 0, 0, 0); \
      _Pragma("unroll")                                                          \
      for (int q = 0; q < 4; ++q){                                               \
        unsigned int u = (__float_as_uint(acc[q]) & maskv) | tcv;                \
        int rr = rg * 4 + q;                                                     \
        unsigned int nv2;                                                        \
        asm("v_med3_u32 %0, %1, %2, %3" : "=v"(nv2) : "v"(u), "v"(v1[rr]), "v"(v2[rr])); \
        v2[rr] = nv2;                                                            \
        v1[rr] = max(u, v1[rr]);                                                 \
      }                                                                          \
    }                                                                            \
  }

__global__ __launch_bounds__(512, 4) void vq_main_mfma(
    const float* __restrict__ inputs,
    const unsigned short* __restrict__ ehi,
    const unsigned short* __restrict__ elo,
    const float* __restrict__ emb,
    float* __restrict__ out_q, float* __restrict__ out_idx,
    float* __restrict__ part, int* __restrict__ cnt, int* __restrict__ list)
{
    const int L = threadIdx.x & 63;
    const int w = threadIdx.x >> 6;
    const int rowbase = blockIdx.x * 32;

    __shared__ float snorm[32];
    __shared__ unsigned int sv1[8][32];
    __shared__ unsigned int sv2[8][32];
    __shared__ int          scol[8][32];

    // A fragments + per-row norms (all waves load the same 32 rows)
    short8 ahi[2], alo[2];
    #pragma unroll
    for (int rg = 0; rg < 2; ++rg){
        const float* xr = inputs + (size_t)(rowbase + rg*16 + (L & 15)) * DIM + (L >> 4) * 8;
        float4 p0 = *(const float4*)xr;
        float4 p1 = *(const float4*)(xr + 4);
        float f[8] = {p0.x, p0.y, p0.z, p0.w, p1.x, p1.y, p1.z, p1.w};
        short8 h, l;
        #pragma unroll
        for (int i = 0; i < 8; i++){
            unsigned short hb = bf16_rne(f[i]);
            h[i] = (short)hb;
            l[i] = (short)bf16_rne(f[i] - bf16_to_f(hb));
        }
        ahi[rg] = h; alo[rg] = l;
        float s = dot4(p0, p0) + dot4(p1, p1);
        s += __shfl_xor(s, 16, 64);
        s += __shfl_xor(s, 32, 64);
        if (w == 0 && (L >> 4) == 0) snorm[rg*16 + L] = sqrtf(s);
    }
    __syncthreads();

    f32x4 cbias[2];
    #pragma unroll
    for (int rg = 0; rg < 2; ++rg){
        #pragma unroll
        for (int q = 0; q < 4; ++q)
            cbias[rg][q] = 2.0f * snorm[rg*16 + (L >> 4)*4 + q];
    }

    unsigned int maskv = 0xFFFFFFC0u;
    asm("" : "+v"(maskv));   // pin mask in VGPR so (x & m) | t fuses to v_and_or_b32

    unsigned int v1[8], v2[8];
    #pragma unroll
    for (int r = 0; r < 8; r++){ v1[r] = 0u; v2[r] = 0u; }

    const int c0 = w * 1024;
    const unsigned short* ehp = ehi + (size_t)(c0 + (L & 15)) * DIM + (L >> 4) * 8;
    const unsigned short* elp = elo + (size_t)(c0 + (L & 15)) * DIM + (L >> 4) * 8;

    for (int t = 0; t < 64; t += 2){
        short8 b0h = *(const short8*)(ehp);
        short8 b0l = *(const short8*)(elp);
        short8 b1h = *(const short8*)(ehp + 512);
        short8 b1l = *(const short8*)(elp + 512);
        ehp += 1024; elp += 1024;
        PROC(b0h, b0l, 63 - t);
        PROC(b1h, b1l, 62 - t);
    }

    // in-register reduction over the 16 cols (lane&15), exact top-2 merge
    unsigned int p1[8];
    #pragma unroll
    for (int r = 0; r < 8; r++) p1[r] = v1[r];
    #pragma unroll
    for (int m = 1; m < 16; m <<= 1){
        #pragma unroll
        for (int r = 0; r < 8; r++){
            unsigned int ov1 = __shfl_xor(v1[r], m, 64);
            unsigned int ov2 = __shfl_xor(v2[r], m, 64);
            unsigned int mn = min(v1[r], ov1);
            v2[r] = max(max(v2[r], ov2), mn);
            v1[r] = max(v1[r], ov1);
        }
    }
    // recover winning col via ballot (lowest matching lane = lowest col = first occurrence)
    int colr[8];
    #pragma unroll
    for (int r = 0; r < 8; r++){
        unsigned long long bm = __ballot(p1[r] == v1[r]);
        unsigned int grp = (unsigned int)((bm >> ((L >> 4) << 4)) & 0xFFFFull);
        colr[r] = __ffs(grp) - 1;
    }

    if ((L & 15) == 0){
        #pragma unroll
        for (int rg = 0; rg < 2; ++rg){
            #pragma unroll
            for (int q = 0; q < 4; ++q){
                int row = rg*16 + (L >> 4)*4 + q;   // C row = (lane>>4)*4 + reg
                sv1[w][row] = v1[rg*4 + q];
                sv2[w][row] = v2[rg*4 + q];
                scol[w][row] = colr[rg*4 + q];
            }
        }
    }
    __syncthreads();

    // epilogue (threads 0..31): merge 8 wave-slices, gather, loss, flag
    if (threadIdx.x < 32){
        int r = threadIdx.x;
        unsigned int b1 = 0u, b2 = 0u; int bw = 0, bc = 0;
        #pragma unroll
        for (int s = 0; s < 8; ++s){
            unsigned int u1 = sv1[s][r];
            unsigned int u2 = sv2[s][r];
            unsigned int mn = min(b1, u1);
            b2 = max(max(b2, u2), mn);
            bool g = u1 > b1;
            if (g){ b1 = u1; bw = s; bc = scol[s][r]; }
        }
        int t = 63 - (int)(b1 & 63u);
        int k = bw*1024 + t*16 + bc;
        int row = rowbase + r;
        out_idx[row] = (float)k;

        // gather code row, write quantized output, per-row squared error
        const float4* ep = (const float4*)(emb + (size_t)k * DIM);
        const float4* xr = (const float4*)(inputs + (size_t)row * DIM);
        float4* oq = (float4*)(out_q + (size_t)row * DIM);
        float s = 0.f;
        #pragma unroll
        for (int i = 0; i < 8; i++){
            float4 q = ep[i], x = xr[i];
            oq[i] = q;
            float dx = q.x - x.x, dy = q.y - x.y, dz = q.z - x.z, dw = q.w - x.w;
            s += dx*dx + dy*dy + dz*dz + dw*dw;
        }

        // flag near-ties for exact fp32 refinement
        float f1 = __uint_as_float(b1 & 0xFFFFFFC0u);
        float f2 = __uint_as_float(b2 & 0xFFFFFFC0u);
        if (f1 - f2 <= snorm[r] * EPS_REL){
            int pos = atomicAdd(cnt, 1);
            if (pos < FLAG_CAP) list[pos] = row;
        }

        // 32-lane reduction of the block's loss partial
        #pragma unroll
        for (int off = 16; off; off >>= 1) s += __shfl_down(s, off, 64);
        if (r == 0) part[blockIdx.x] = s;
    }
}

// -------- refine: exact fp32 argmax for flagged rows + patch + loss sum ------
__global__ __launch_bounds__(256) void vq_refine(
    const float* __restrict__ inputs, const float* __restrict__ emb,
    float* __restrict__ out_q, float* __restrict__ out_idx,
    const int* __restrict__ list, int* __restrict__ cnt,
    float* __restrict__ corrd, const float* __restrict__ part,
    float* __restrict__ out_loss)
{
    int n = cnt[0]; if (n > FLAG_CAP) n = FLAG_CAP;
    __shared__ float sv[4]; __shared__ int si[4];
    __shared__ int sbi;
    for (int j = blockIdx.x; j < n; j += gridDim.x){
        int row = list[j];
        const float4* xr = (const float4*)(inputs + (size_t)row * DIM);
        float4 x0 = xr[0], x1 = xr[1], x2 = xr[2], x3 = xr[3];
        float4 x4 = xr[4], x5 = xr[5], x6 = xr[6], x7 = xr[7];
        float bv = -3.0e38f; int bi = 0x7fffffff;
        for (int c = threadIdx.x; c < KCODES; c += 256){
            const float4* ep = (const float4*)(emb + (size_t)c * DIM);
            float d = dot4(x0, ep[0]) + dot4(x1, ep[1]) + dot4(x2, ep[2]) + dot4(x3, ep[3])
                    + dot4(x4, ep[4]) + dot4(x5, ep[5]) + dot4(x6, ep[6]) + dot4(x7, ep[7]);
            if (d > bv || (d == bv && c < bi)){ bv = d; bi = c; }
        }
        #pragma unroll
        for (int off = 32; off; off >>= 1){
            float ov = __shfl_down(bv, off, 64);
            int   oi = __shfl_down(bi, off, 64);
            if (ov > bv || (ov == bv && oi < bi)){ bv = ov; bi = oi; }
        }
        if ((threadIdx.x & 63) == 0){ sv[threadIdx.x >> 6] = bv; si[threadIdx.x >> 6] = bi; }
        __syncthreads();
        if (threadIdx.x == 0){
            #pragma unroll
            for (int q = 1; q < 4; q++){
                if (sv[q] > bv || (sv[q] == bv && si[q] < bi)){ bv = sv[q]; bi = si[q]; }
            }
            sbi = bi;
        }
        __syncthreads();
        int knew = sbi;
        int kold = (int)out_idx[row];
        // lanes 0..31: per-element loss delta; patch row if index changed
        if (threadIdx.x < 32){
            float x  = inputs[(size_t)row * DIM + threadIdx.x];
            float en = emb[(size_t)knew * DIM + threadIdx.x];
            float eo = emb[(size_t)kold * DIM + threadIdx.x];
            float d  = (en - x)*(en - x) - (eo - x)*(eo - x);
            #pragma unroll
            for (int off = 16; off; off >>= 1) d += __shfl_down(d, off, 64);
            if (knew != kold) out_q[(size_t)row * DIM + threadIdx.x] = en;
            if (threadIdx.x == 0){
                corrd[j] = (knew != kold) ? d : 0.0f;
                if (knew != kold) out_idx[row] = (float)knew;
            }
        }
        __syncthreads();
    }

    // last-block loss finalize (ticket)
    __shared__ int tkt;
    if (threadIdx.x == 0){
        __threadfence();
        tkt = atomicAdd(cnt + 1, 1);
    }
    __syncthreads();
    if (tkt == (int)gridDim.x - 1){
        __threadfence();
        float s = 0.f;
        for (int i = threadIdx.x; i < NBLK; i += 256) s += part[i];
        for (int j = threadIdx.x; j < n; j += 256) s += corrd[j];
        #pragma unroll
        for (int off = 32; off; off >>= 1) s += __shfl_down(s, off, 64);
        __shared__ float sp[4];
        if ((threadIdx.x & 63) == 0) sp[threadIdx.x >> 6] = s;
        __syncthreads();
        if (threadIdx.x == 0)
            *out_loss = (sp[0] + sp[1] + sp[2] + sp[3]) * (1.0f / ((float)NROWS * (float)DIM));
    }
}

extern "C" void kernel_launch(void* const* d_in, const int* in_sizes, int n_in,
                              void* d_out, int out_size, void* d_ws, size_t ws_size,
                              hipStream_t stream) {
    const float* inputs = (const float*)d_in[0];
    const float* emb    = (const float*)d_in[1];
    float* out      = (float*)d_out;
    float* out_q    = out;                       // [32768*32]
    float* out_loss = out + (size_t)NROWS * DIM; // [1]
    float* out_idx  = out_loss + 1;              // [32768] as float

    char* ws = (char*)d_ws;
    unsigned short* ehi   = (unsigned short*)(ws + WS_EHI);
    unsigned short* elo   = (unsigned short*)(ws + WS_ELO);
    float*          part  = (float*)(ws + WS_PART);
    int*            cnt   = (int*)(ws + WS_CNT);
    int*            list  = (int*)(ws + WS_LIST);
    float*          corrd = (float*)(ws + WS_CORR);

    vq_prep     <<<dim3(128),  dim3(256), 0, stream>>>(emb, ehi, elo, cnt);
    vq_main_mfma<<<dim3(NBLK), dim3(512), 0, stream>>>(inputs, ehi, elo, emb,
                                                       out_q, out_idx, part, cnt, list);
    vq_refine   <<<dim3(256),  dim3(256), 0, stream>>>(inputs, emb, out_q, out_idx,
                                                       list, cnt, corrd, part, out_loss);
}